// Round 5
// baseline (706.300 us; speedup 1.0000x reference)
//
#include <hip/hip_runtime.h>

typedef unsigned short u16;
typedef unsigned int   u32;
typedef __attribute__((ext_vector_type(4))) float  f32x4;
typedef __attribute__((ext_vector_type(8))) __bf16 bf16x8;

// ---------------- constants ----------------
#define BATCH 8
#define SEQ   2048
#define DMODEL 1024
#define DK    512
#define DV    512
#define SCALE 0.044194173824159216f

__device__ __forceinline__ u16 f2bf(float f) {
  u32 u = __float_as_uint(f);
  return (u16)((u + 0x7fffu + ((u >> 16) & 1u)) >> 16);
}

// mask dtype mode: 0 = int32, 1 = uint8, 2 = float32
__device__ __forceinline__ bool read_mask(const void* p, int idx, int mode) {
  if (mode == 1) return ((const unsigned char*)p)[idx] != 0;
  if (mode == 2) return ((const float*)p)[idx] != 0.0f;
  return ((const int*)p)[idx] != 0;
}

// async global->LDS, 16B per lane, dest = lds + lane*16 (wave-uniform base)
__device__ __forceinline__ void gl_lds16(const u16* g, u16* l) {
  __builtin_amdgcn_global_load_lds(
      (const __attribute__((address_space(1))) u32*)g,
      (__attribute__((address_space(3))) u32*)l, 16, 0, 0);
}

// ---------------- kernel 0: detect mask dtype ----------------
__global__ void detect_mode(const int* __restrict__ qp, int* __restrict__ flag) {
  __shared__ int f;
  if (threadIdx.x == 0) f = 0;
  __syncthreads();
  int local = 0;
  for (int i = threadIdx.x; i < 4096; i += 256) {
    int v = qp[i];
    if (v == 0x3F800000) local |= 2;
    else if (v != 0 && v != 1 && v != -1) local |= 1;
  }
  if (local) atomicOr(&f, local);
  __syncthreads();
  if (threadIdx.x == 0) {
    int m = 0;
    if (f & 2) m = 2; else if (f & 1) m = 1;
    *flag = m;
  }
}

// ---------------- kernel 1: W [1024][512] f32 -> Wt [512][1024] bf16 ----------------
__global__ __launch_bounds__(256) void wt_transpose(const float* __restrict__ W0,
                                                    const float* __restrict__ W1,
                                                    const float* __restrict__ W2,
                                                    u16* __restrict__ dst) {
  const float* W = (blockIdx.z == 0) ? W0 : (blockIdx.z == 1) ? W1 : W2;
  u16* out = dst + (size_t)blockIdx.z * (DK * DMODEL);
  __shared__ float T[32][33];
  int k0 = blockIdx.x * 32, n0 = blockIdx.y * 32;
  int tx = threadIdx.x, ty = threadIdx.y;
#pragma unroll
  for (int i = 0; i < 4; ++i) {
    int r = ty + i * 8;
    T[r][tx] = W[(size_t)(k0 + r) * DK + n0 + tx];
  }
  __syncthreads();
#pragma unroll
  for (int i = 0; i < 4; ++i) {
    int r = ty + i * 8;
    out[(size_t)(n0 + r) * DMODEL + k0 + tx] = f2bf(T[tx][r]);
  }
}

// ---------------- kernel 2: f32 -> bf16 elementwise ----------------
__global__ __launch_bounds__(256) void convert_bf16(const float* __restrict__ src,
                                                    u16* __restrict__ dst) {
  int i = (blockIdx.x * 256 + threadIdx.x) * 8;
  f32x4 a = *(const f32x4*)(src + i);
  f32x4 b = *(const f32x4*)(src + i + 4);
  uint4 o;
  o.x = (u32)f2bf(a[0]) | ((u32)f2bf(a[1]) << 16);
  o.y = (u32)f2bf(a[2]) | ((u32)f2bf(a[3]) << 16);
  o.z = (u32)f2bf(b[0]) | ((u32)f2bf(b[1]) << 16);
  o.w = (u32)f2bf(b[2]) | ((u32)f2bf(b[3]) << 16);
  *(uint4*)(dst + i) = o;
}

// ---------------- kernel 3: projection GEMM (m97 structure) ----------------
// C[16384][512] = A(bf16)[16384][1024] * Wt(bf16)[512][1024]^T
// Epilogue fragment layouts:
//   Qf/Kf (z!=2): off(row,d) = (row>>4)*8192 + (d>>5)*512 + (row&15)*32 + (d&31)
//   Vf    (z==2): off(dv,s)  = b*S*DV + (dv>>4)*32768 + ((s&2047)>>5)*512
//                              + (dv&15)*32 + rho(s&31)
//   where rho(x) = ((x&15)>>2)*8 + (x&3) + ((x>>4)<<2)  -- key permutation so the
//   attention kernel's in-register P^T (C-layout: key = quad*4+r per 16-half)
//   feeds PV's A-operand directly with no transpose.
__global__ __launch_bounds__(256, 3) void proj_gemm(const u16* __restrict__ A,
                                                    const u16* __restrict__ Wt_base,
                                                    int z0, u16* __restrict__ dst0,
                                                    u16* __restrict__ dst1) {
  int z = z0 + blockIdx.z;
  const u16* Wt = Wt_base + (size_t)z * (DK * DMODEL);
  u16* dst = (z == 2) ? dst1 : dst0;
  int n0 = blockIdx.x * 128, m0 = blockIdx.y * 128;

  __shared__ __align__(16) u16 As[128 * 64];
  __shared__ __align__(16) u16 Bs[128 * 64];

  int tid = threadIdx.x, lane = tid & 63, w = tid >> 6;
  int wm = w & 1, wn = w >> 1;
  int l15 = lane & 15, lg = lane >> 4;
  int r3 = lane >> 3, c7 = lane & 7;
  int csw = c7 ^ r3;

  f32x4 acc[4][4];
#pragma unroll
  for (int m = 0; m < 4; ++m)
#pragma unroll
    for (int n = 0; n < 4; ++n) acc[m][n] = (f32x4)0.0f;

  for (int k0 = 0; k0 < DMODEL; k0 += 64) {
    __syncthreads();
#pragma unroll
    for (int u = 0; u < 4; ++u) {
      int t = w * 4 + u;
      gl_lds16(A  + (size_t)(m0 + t * 8 + r3) * DMODEL + k0 + csw * 8, &As[t * 512]);
      gl_lds16(Wt + (size_t)(n0 + t * 8 + r3) * DMODEL + k0 + csw * 8, &Bs[t * 512]);
    }
    __syncthreads();
#pragma unroll
    for (int ks = 0; ks < 2; ++ks) {
      bf16x8 af[4], bfv[4];
#pragma unroll
      for (int m = 0; m < 4; ++m) {
        int row = wm * 64 + m * 16 + l15;
        af[m] = *(const bf16x8*)&As[row * 64 + (((ks * 4 + lg) ^ (l15 & 7)) * 8)];
      }
#pragma unroll
      for (int n = 0; n < 4; ++n) {
        int row = wn * 64 + n * 16 + l15;
        bfv[n] = *(const bf16x8*)&Bs[row * 64 + (((ks * 4 + lg) ^ (l15 & 7)) * 8)];
      }
#pragma unroll
      for (int m = 0; m < 4; ++m)
#pragma unroll
        for (int n = 0; n < 4; ++n)
          acc[m][n] = __builtin_amdgcn_mfma_f32_16x16x32_bf16(af[m], bfv[n], acc[m][n], 0, 0, 0);
    }
  }

  if (z != 2) {
#pragma unroll
    for (int m = 0; m < 4; ++m) {
      int rowb = m0 + wm * 64 + m * 16;
#pragma unroll
      for (int n = 0; n < 4; ++n) {
        int col = n0 + wn * 64 + n * 16 + l15;
        size_t base = (size_t)(rowb >> 4) * 8192 + (size_t)(col >> 5) * 512 + (col & 31);
#pragma unroll
        for (int r = 0; r < 4; ++r)
          dst[base + (lg * 4 + r) * 32] = f2bf(acc[m][n][r]);
      }
    }
  } else {
    // V fragment layout with rho key-permutation; rho0 = lg*8 + (m&1)*4, +r contiguous
#pragma unroll
    for (int m = 0; m < 4; ++m) {
      int row0 = m0 + wm * 64 + m * 16 + lg * 4;
      int b = row0 >> 11, s0 = row0 & 2047;
#pragma unroll
      for (int n = 0; n < 4; ++n) {
        int dv = n0 + wn * 64 + n * 16 + l15;
        size_t off = (size_t)b * (SEQ * DV) + (size_t)(dv >> 4) * 32768 +
                     (size_t)(s0 >> 5) * 512 + (dv & 15) * 32 + lg * 8 + (m & 1) * 4;
        u16 tmp[4] __attribute__((aligned(8)));
#pragma unroll
        for (int r = 0; r < 4; ++r) tmp[r] = f2bf(acc[m][n][r]);
        *(uint2*)&dst[off] = *(const uint2*)tmp;
      }
    }
  }
}

// ---------------- kernel 4: flash attention v5 — barrier-free, zero LDS ----------------
// Block = 128 thr = 2 independent waves (dv halves share K via L1).
// Wave: 16 q-rows x 256 dv, KTILE=32. S^T = mfma(K_frag, Q_frag) -> q = lane&15;
// softmax rows reduce with 2 shfl_xor; P^T feeds PV directly (V key-permuted).
__global__ __launch_bounds__(128, 2) void attn_kernel(
    const u16* __restrict__ Qf, const u16* __restrict__ Kf,
    const u16* __restrict__ Vf, const void* __restrict__ qpad,
    const void* __restrict__ kvpad, const int* __restrict__ flag,
    float* __restrict__ out) {
  int tid = threadIdx.x;
  int lane = tid & 63;
  int dvh = tid >> 6;                 // wave id = dv half
  int l15 = lane & 15, lg = lane >> 4;
  int bi = blockIdx.x;
  int b = bi & 7;
  int qt = 127 - (bi >> 3);           // big q-tiles dispatch first
  int q0 = qt * 16;
  int mode = *flag;
  int lanoff = l15 * 32 + lg * 8;
  int q = q0 + l15;                   // this lane's softmax row

  const u16* Qb = Qf + (size_t)b * (SEQ * DK);
  const u16* Kb = Kf + (size_t)b * (SEQ * DK);
  const u16* Vb = Vf + (size_t)b * (SEQ * DV) + (size_t)(dvh * 16) * 32768;

  // resident Q fragment: 16 rows x 512 d -> 64 VGPRs
  bf16x8 qf[16];
  {
    const u16* qp = Qb + (size_t)qt * 8192 + lanoff;
#pragma unroll
    for (int ks = 0; ks < 16; ++ks) qf[ks] = *(const bf16x8*)(qp + ks * 512);
  }

  f32x4 o[16];
#pragma unroll
  for (int g = 0; g < 16; ++g) o[g] = (f32x4)0.0f;

  float mo = -1e38f, lsum = 0.0f;
  int nkt = (q0 + 47) >> 5;

  for (int kt = 0; kt < nkt; ++kt) {
    int k0 = kt * 32;

    // ---- S^T = K Q^T : D[key][q], frag0 keys k0..+15, frag1 k0+16..+31 ----
    f32x4 s0 = (f32x4)0.0f, s1 = (f32x4)0.0f;
    {
      const u16* kp = Kb + (size_t)(k0 >> 4) * 8192 + lanoff;
#pragma unroll
      for (int ks = 0; ks < 16; ++ks) {
        bf16x8 a0 = *(const bf16x8*)(kp + ks * 512);
        bf16x8 a1 = *(const bf16x8*)(kp + 8192 + ks * 512);
        s0 = __builtin_amdgcn_mfma_f32_16x16x32_bf16(a0, qf[ks], s0, 0, 0, 0);
        s1 = __builtin_amdgcn_mfma_f32_16x16x32_bf16(a1, qf[ks], s1, 0, 0, 0);
      }
    }

    // ---- scale + mask (key = k0 + lg*4 + r [+16], q = q0 + l15) ----
    float sv0[4], sv1[4];
#pragma unroll
    for (int r = 0; r < 4; ++r) {
      int key0 = k0 + lg * 4 + r;
      bool msk0 = read_mask(kvpad, b * SEQ + key0, mode) || (key0 > q);
      bool msk1 = read_mask(kvpad, b * SEQ + key0 + 16, mode) || (key0 + 16 > q);
      sv0[r] = msk0 ? -__builtin_inff() : s0[r] * SCALE;
      sv1[r] = msk1 ? -__builtin_inff() : s1[r] * SCALE;
    }

    // ---- row max (per q = l15): local 8, then xor 16, 32 ----
    float tmax = fmaxf(fmaxf(fmaxf(sv0[0], sv0[1]), fmaxf(sv0[2], sv0[3])),
                       fmaxf(fmaxf(sv1[0], sv1[1]), fmaxf(sv1[2], sv1[3])));
    tmax = fmaxf(tmax, __shfl_xor(tmax, 16));
    tmax = fmaxf(tmax, __shfl_xor(tmax, 32));

    float mn = fmaxf(mo, fmaxf(tmax, -1e38f)); // clamp: fully-masked rows stay finite
    float al = __expf(mo - mn);
    mo = mn;

    float p0[4], p1[4];
    float psum = 0.0f;
#pragma unroll
    for (int r = 0; r < 4; ++r) {
      p0[r] = __expf(sv0[r] - mn);
      p1[r] = __expf(sv1[r] - mn);
      psum += p0[r] + p1[r];
    }
    psum += __shfl_xor(psum, 16);
    psum += __shfl_xor(psum, 32);
    lsum = lsum * al + psum;

    // ---- pack P^T A-fragment (slot order matches V's rho permutation) ----
    u16 pk[8] __attribute__((aligned(16)));
#pragma unroll
    for (int r = 0; r < 4; ++r) { pk[r] = f2bf(p0[r]); pk[4 + r] = f2bf(p1[r]); }
    bf16x8 pa = *(const bf16x8*)pk;

    // ---- rescale O: alpha for O-row (lg*4+r) fetched from lane lg*4+r ----
    float alr[4];
#pragma unroll
    for (int r = 0; r < 4; ++r) alr[r] = __shfl(al, lg * 4 + r);
#pragma unroll
    for (int g = 0; g < 16; ++g)
#pragma unroll
      for (int r = 0; r < 4; ++r) o[g][r] *= alr[r];

    // ---- O += P V : V fragment-direct, key-permuted ----
    {
      const u16* vp = Vb + (size_t)kt * 512 + lanoff;
#pragma unroll
      for (int g = 0; g < 16; ++g) {
        bf16x8 bv = *(const bf16x8*)(vp + (size_t)g * 32768);
        o[g] = __builtin_amdgcn_mfma_f32_16x16x32_bf16(pa, bv, o[g], 0, 0, 0);
      }
    }
  }

  // ---- epilogue: normalize + masks (O rows = lg*4+r, via shuffle from lane) ----
  {
    bool qpm = read_mask(qpad, b * SEQ + q, mode);
    float linv = (lsum > 0.0f && !qpm) ? 1.0f / lsum : 0.0f;
    float lr[4];
#pragma unroll
    for (int r = 0; r < 4; ++r) lr[r] = __shfl(linv, lg * 4 + r);
#pragma unroll
    for (int g = 0; g < 16; ++g) {
      int dv = dvh * 256 + g * 16 + l15;
#pragma unroll
      for (int r = 0; r < 4; ++r) {
        int row = q0 + lg * 4 + r;
        out[(size_t)(b * SEQ + row) * DV + dv] = o[g][r] * lr[r];
      }
    }
  }
}

// ---------------- workspace layout (bytes) ----------------
// Abf  [16384][1024] bf16 : 0         .. 33554432   (sq first, then skv - reused)
// Qf                      : 33554432  .. 50331648
// Kf                      : 50331648  .. 67108864
// Vf                      : 67108864  .. 83886080
// Wt (3x [512][1024] bf16): 83886080  .. 87031808
// flag (int)              : 87031808  .. 87031812
extern "C" void kernel_launch(void* const* d_in, const int* in_sizes, int n_in,
                              void* d_out, int out_size, void* d_ws, size_t ws_size,
                              hipStream_t stream) {
  const float* sq  = (const float*)d_in[0];
  const float* skv = (const float*)d_in[1];
  const void* qp   = d_in[2];
  const void* kvp  = d_in[3];
  const float* Wq  = (const float*)d_in[4];
  const float* Wk  = (const float*)d_in[5];
  const float* Wv  = (const float*)d_in[6];
  char* ws = (char*)d_ws;

  u16* Abf = (u16*)ws;
  u16* Qf  = (u16*)(ws + 33554432);
  u16* Kf  = (u16*)(ws + 50331648);
  u16* Vf  = (u16*)(ws + 67108864);
  u16* Wt  = (u16*)(ws + 83886080);
  int* flag = (int*)(ws + 87031808);

  wt_transpose<<<dim3(32, 16, 3), dim3(32, 8, 1), 0, stream>>>(Wq, Wk, Wv, Wt);
  detect_mode<<<1, 256, 0, stream>>>((const int*)qp, flag);

  convert_bf16<<<8192, 256, 0, stream>>>(sq, Abf);
  proj_gemm<<<dim3(4, 128, 1), dim3(256), 0, stream>>>(Abf, Wt, 0, Qf, Qf);

  convert_bf16<<<8192, 256, 0, stream>>>(skv, Abf);
  proj_gemm<<<dim3(4, 128, 2), dim3(256), 0, stream>>>(Abf, Wt, 1, Kf, Vf);

  attn_kernel<<<dim3(1024), dim3(128), 0, stream>>>(Qf, Kf, Vf, qp, kvp, flag,
                                                    (float*)d_out);
}